// Round 1
// baseline (421.841 us; speedup 1.0000x reference)
//
#include <hip/hip_runtime.h>
#include <math.h>

// Problem constants
#define KC 1024      // num codes
#define DD 256       // embedding dim
#define NROWS 32768  // 32 * 32 * 32 (B*H*W)
#define NELEM 8388608 // NROWS * DD

// ---------------------------------------------------------------------------
// init: zero counts + loss accumulator (ws is poisoned 0xAA before each call)
// ---------------------------------------------------------------------------
__global__ void vq_init_kernel(int* __restrict__ counts, float* __restrict__ loss_acc) {
    int t = blockIdx.x * 256 + threadIdx.x;
    if (t < KC) counts[t] = 0;
    if (t == 0) *loss_acc = 0.0f;
}

// ---------------------------------------------------------------------------
// c_sq[k] = ||emb[k]||^2.  256 blocks x 256 threads, 4 codes/block (1/wave).
// ---------------------------------------------------------------------------
__global__ void vq_csq_kernel(const float* __restrict__ emb, float* __restrict__ c_sq) {
    int k = blockIdx.x * 4 + (threadIdx.x >> 6);
    int lane = threadIdx.x & 63;
    float4 v = *(const float4*)(emb + (size_t)k * DD + lane * 4);
    float s = v.x * v.x + v.y * v.y + v.z * v.z + v.w * v.w;
    #pragma unroll
    for (int off = 32; off > 0; off >>= 1) s += __shfl_down(s, off);
    if (lane == 0) c_sq[k] = s;
}

// ---------------------------------------------------------------------------
// dist+argmin: per block 32 rows, loop over 16 chunks of 64 codes,
// each chunk in 4 sub-chunks of 64 dims.  fp32 VALU GEMM-like.
// LDS: z_s 36864 + e_s 18432 + sc_s 9216 = 64512 B -> 2 blocks/CU.
// ---------------------------------------------------------------------------
__global__ __launch_bounds__(256, 2)
void vq_dist_kernel(const float* __restrict__ z, const float* __restrict__ emb,
                    const float* __restrict__ c_sq, int* __restrict__ idx_out,
                    int* __restrict__ counts) {
    __shared__ float z_s[256][36];  // [dim][row], pad 36 -> conflict-free
    __shared__ float e_s[64][72];   // [code_local][dim_local], pad 72
    __shared__ float sc_s[64][36];  // [code_local][row]

    const int tid = threadIdx.x;
    const int n0 = blockIdx.x * 32;
    const int b = n0 >> 10;
    const int hw0 = n0 & 1023;

    // stage z tile transposed: z_s[c][r] = z[b][c][hw0+r]
    {
        int r = tid & 31;
        int cg = tid >> 5;  // 0..7
        const float* zp = z + (size_t)b * (DD * 1024) + hw0 + r;
        #pragma unroll 4
        for (int c = cg; c < DD; c += 8)
            z_s[c][r] = zp[(size_t)c * 1024];
    }

    float bestv = 3.0e38f;
    int besti = 0;
    const int tr = tid & 7;    // row group: rows 4*tr .. 4*tr+3
    const int tc = tid >> 3;   // code group 0..31: codes 2*tc, 2*tc+1

    for (int kc = 0; kc < 16; ++kc) {
        const int k0 = kc << 6;
        float s00 = 0.f, s10 = 0.f, s20 = 0.f, s30 = 0.f;
        float s01 = 0.f, s11 = 0.f, s21 = 0.f, s31 = 0.f;

        for (int dc = 0; dc < 4; ++dc) {
            const int d0 = dc << 6;
            __syncthreads();  // protect e_s (prev readers done)
            // stage e chunk: e_s[kl][dl] = emb[k0+kl][d0+dl]
            {
                int dl4 = (tid & 15) << 2;
                int klb = tid >> 4;  // 0..15
                const float* ep = emb + (size_t)k0 * DD + d0 + dl4;
                #pragma unroll
                for (int it = 0; it < 4; ++it) {
                    int kk = it * 16 + klb;
                    float4 v = *(const float4*)(ep + (size_t)kk * DD);
                    e_s[kk][dl4]     = v.x;
                    e_s[kk][dl4 + 1] = v.y;
                    e_s[kk][dl4 + 2] = v.z;
                    e_s[kk][dl4 + 3] = v.w;
                }
            }
            __syncthreads();
            // accumulate dot products
            #pragma unroll 16
            for (int d = 0; d < 64; ++d) {
                float4 z4 = *(const float4*)&z_s[d0 + d][tr << 2];
                float ea = e_s[2 * tc][d];
                float eb = e_s[2 * tc + 1][d];
                s00 += z4.x * ea; s10 += z4.y * ea; s20 += z4.z * ea; s30 += z4.w * ea;
                s01 += z4.x * eb; s11 += z4.y * eb; s21 += z4.z * eb; s31 += z4.w * eb;
            }
        }
        // scores = ||e||^2 - 2*dot  (row-constant ||z||^2 dropped; argmin invariant)
        {
            float ca = c_sq[k0 + 2 * tc];
            float cb = c_sq[k0 + 2 * tc + 1];
            int r4 = tr << 2;
            sc_s[2 * tc][r4]     = ca - 2.f * s00;
            sc_s[2 * tc][r4 + 1] = ca - 2.f * s10;
            sc_s[2 * tc][r4 + 2] = ca - 2.f * s20;
            sc_s[2 * tc][r4 + 3] = ca - 2.f * s30;
            sc_s[2 * tc + 1][r4]     = cb - 2.f * s01;
            sc_s[2 * tc + 1][r4 + 1] = cb - 2.f * s11;
            sc_s[2 * tc + 1][r4 + 2] = cb - 2.f * s21;
            sc_s[2 * tc + 1][r4 + 3] = cb - 2.f * s31;
        }
        __syncthreads();
        // running argmin (first-min tie-break: ascending k, strict <)
        if (tid < 32) {
            #pragma unroll 8
            for (int kl = 0; kl < 64; ++kl) {
                float v = sc_s[kl][tid];
                if (v < bestv) { bestv = v; besti = k0 + kl; }
            }
        }
        // next kc's first __syncthreads protects sc_s before rewrite
    }

    if (tid < 32) {
        idx_out[n0 + tid] = besti;
        atomicAdd(&counts[besti], 1);
    }
}

// ---------------------------------------------------------------------------
// gather + transpose write + loss: block = 64 rows, LDS transpose so both
// emb reads and output writes are coalesced.  Fused (q-z)^2 reduction.
// ---------------------------------------------------------------------------
__global__ __launch_bounds__(256, 2)
void vq_gather_kernel(const float* __restrict__ z, const float* __restrict__ emb,
                      const int* __restrict__ idx, float* __restrict__ out,
                      float* __restrict__ loss_acc) {
    __shared__ float Q[64][257];
    __shared__ int idx_s[64];
    __shared__ float wsum[4];

    const int tid = threadIdx.x;
    const int n0 = blockIdx.x * 64;
    const int b = n0 >> 10;
    const int hw0 = n0 & 1023;

    if (tid < 64) idx_s[tid] = idx[n0 + tid];
    __syncthreads();

    // stage Q[r][c] = emb[idx[r]][c], coalesced float4 reads
    {
        int r = tid >> 2;       // 0..63
        int q4 = tid & 3;       // 0..3
        const float* ep = emb + (size_t)idx_s[r] * DD;
        #pragma unroll
        for (int i = 0; i < 16; ++i) {
            int d = (q4 << 2) + (i << 4);  // 4*q4 + 16*i
            float4 v = *(const float4*)(ep + d);
            Q[r][d]     = v.x;
            Q[r][d + 1] = v.y;
            Q[r][d + 2] = v.z;
            Q[r][d + 3] = v.w;
        }
    }
    __syncthreads();

    float acc = 0.f;
    const int lane = tid & 63;
    const int w = tid >> 6;
    const size_t base = (size_t)b * (DD * 1024) + hw0 + lane;
    for (int c = w; c < DD; c += 4) {
        float q = Q[lane][c];
        size_t a = base + (size_t)c * 1024;
        float zv = z[a];
        out[a] = q;
        float d = q - zv;
        acc += d * d;
    }
    #pragma unroll
    for (int off = 32; off > 0; off >>= 1) acc += __shfl_down(acc, off);
    if (lane == 0) wsum[w] = acc;
    __syncthreads();
    if (tid == 0) atomicAdd(loss_acc, wsum[0] + wsum[1] + wsum[2] + wsum[3]);
}

// ---------------------------------------------------------------------------
// finalize: loss scalar + perplexity from counts
// ---------------------------------------------------------------------------
__global__ void vq_finalize_kernel(const int* __restrict__ counts,
                                   const float* __restrict__ loss_acc,
                                   float* __restrict__ out_tail) {
    __shared__ float wsum[4];
    const int tid = threadIdx.x;  // 256
    float s = 0.f;
    #pragma unroll
    for (int k = tid; k < KC; k += 256) {
        float p = (float)counts[k] * (1.0f / (float)NROWS);
        s += p * logf(p + 1e-10f);
    }
    #pragma unroll
    for (int off = 32; off > 0; off >>= 1) s += __shfl_down(s, off);
    const int lane = tid & 63;
    const int w = tid >> 6;
    if (lane == 0) wsum[w] = s;
    __syncthreads();
    if (tid == 0) {
        float ent = wsum[0] + wsum[1] + wsum[2] + wsum[3];
        out_tail[0] = 1.25f * loss_acc[0] * (1.0f / (float)NELEM);  // loss
        out_tail[1] = expf(-ent);                                   // perplexity
    }
}

// ---------------------------------------------------------------------------
extern "C" void kernel_launch(void* const* d_in, const int* in_sizes, int n_in,
                              void* d_out, int out_size, void* d_ws, size_t ws_size,
                              hipStream_t stream) {
    const float* z = (const float*)d_in[0];    // (32,256,32,32)
    const float* emb = (const float*)d_in[1];  // (1024,256)
    float* out = (float*)d_out;                // 8388608 + 2

    float* ws = (float*)d_ws;
    float* c_sq = ws;                          // [1024]
    int* idx = (int*)(ws + KC);                // [32768]
    int* counts = (int*)(ws + KC + NROWS);     // [1024]
    float* loss_acc = ws + KC + NROWS + KC;    // [1]

    hipLaunchKernelGGL(vq_init_kernel, dim3(4), dim3(256), 0, stream, counts, loss_acc);
    hipLaunchKernelGGL(vq_csq_kernel, dim3(256), dim3(256), 0, stream, emb, c_sq);
    hipLaunchKernelGGL(vq_dist_kernel, dim3(1024), dim3(256), 0, stream,
                       z, emb, c_sq, idx, counts);
    hipLaunchKernelGGL(vq_gather_kernel, dim3(512), dim3(256), 0, stream,
                       z, emb, idx, out, loss_acc);
    hipLaunchKernelGGL(vq_finalize_kernel, dim3(1), dim3(256), 0, stream,
                       counts, loss_acc, out + NELEM);
}

// Round 2
// 164.708 us; speedup vs baseline: 2.5611x; 2.5611x over previous
//
#include <hip/hip_runtime.h>
#include <math.h>

// Problem constants
#define KC 1024       // num codes
#define DD 256        // embedding dim
#define NROWS 32768   // 32 * 32 * 32 (B*H*W)
#define NELEM 8388608 // NROWS * DD

typedef _Float16 f16;
typedef __attribute__((ext_vector_type(8))) _Float16 f16x8;
typedef __attribute__((ext_vector_type(16))) float f32x16;

// ---------------------------------------------------------------------------
// init: zero counts + loss accumulator
// ---------------------------------------------------------------------------
__global__ void vq_init_kernel(int* __restrict__ counts, float* __restrict__ loss_acc) {
    int t = blockIdx.x * 256 + threadIdx.x;
    if (t < KC) counts[t] = 0;
    if (t == 0) *loss_acc = 0.0f;
}

// ---------------------------------------------------------------------------
// c_sq[k] = ||emb[k]||^2 in exact fp32
// ---------------------------------------------------------------------------
__global__ void vq_csq_kernel(const float* __restrict__ emb, float* __restrict__ c_sq) {
    int k = blockIdx.x * 4 + (threadIdx.x >> 6);
    int lane = threadIdx.x & 63;
    float4 v = *(const float4*)(emb + (size_t)k * DD + lane * 4);
    float s = v.x * v.x + v.y * v.y + v.z * v.z + v.w * v.w;
    #pragma unroll
    for (int off = 32; off > 0; off >>= 1) s += __shfl_down(s, off);
    if (lane == 0) c_sq[k] = s;
}

// ---------------------------------------------------------------------------
// emb -> fp16, swizzled [kg 32][code 1024][8]  (B-fragment friendly)
// ---------------------------------------------------------------------------
__global__ void vq_embh_kernel(const float* __restrict__ emb, f16* __restrict__ emb_h) {
    int t = blockIdx.x * 256 + threadIdx.x;   // 32768 threads: t = kg*1024 + code
    int code = t & 1023;
    int kg = t >> 10;
    const float* p = emb + (size_t)code * DD + kg * 8;
    float4 v0 = *(const float4*)p;
    float4 v1 = *(const float4*)(p + 4);
    f16x8 h;
    h[0] = (f16)v0.x; h[1] = (f16)v0.y; h[2] = (f16)v0.z; h[3] = (f16)v0.w;
    h[4] = (f16)v1.x; h[5] = (f16)v1.y; h[6] = (f16)v1.z; h[7] = (f16)v1.w;
    *(f16x8*)(emb_h + (size_t)t * 8) = h;
}

// ---------------------------------------------------------------------------
// dist+argmin via MFMA 32x32x16 f16, two-term split z = z_hi + z_r.
// Block: 64 rows, loops 4 chunks x 256 codes; wave w owns codes
// {chunk*256 + w*64 .. +63}. acc[rt][ct] 32x32 tiles, running argmin
// in registers on the C-layout, butterfly + LDS combine at the end.
// LDS: z_s 64 KB + combine 2 KB -> 2 blocks/CU.
// ---------------------------------------------------------------------------
__device__ __forceinline__ void upd(float& bv, int& bi, float v, int i) {
    if (v < bv) { bv = v; bi = i; }
}

__global__ __launch_bounds__(256, 2)
void vq_dist_kernel(const float* __restrict__ z, const f16* __restrict__ emb_h,
                    const float* __restrict__ c_sq, int* __restrict__ idx_out,
                    int* __restrict__ counts) {
    // z_s layout: [term 2][kg 32][row 64][8] f16  (flat 32768 halfs = 64 KB)
    __shared__ f16 z_s[32768];
    __shared__ float bl_v[4][64];
    __shared__ int bl_i[4][64];

    const int tid = threadIdx.x;
    const int n0 = blockIdx.x * 64;
    const int b = n0 >> 10;
    const int hw0 = n0 & 1023;

    // ---- stage z tile: split into hi (fp16) + residual (fp16) ----
    {
        const int r = tid & 63;
        const int kq = tid >> 6;  // 0..3
        const float* zp = z + (size_t)b * (DD * 1024) + hw0 + r;
        #pragma unroll
        for (int it = 0; it < 8; ++it) {
            int kg = kq * 8 + it;
            float v[8];
            #pragma unroll
            for (int j = 0; j < 8; ++j) v[j] = zp[(size_t)(kg * 8 + j) * 1024];
            f16x8 hi, lo;
            #pragma unroll
            for (int j = 0; j < 8; ++j) {
                f16 h = (f16)v[j];
                hi[j] = h;
                lo[j] = (f16)(v[j] - (float)h);
            }
            *(f16x8*)&z_s[(size_t)(kg * 64 + r) * 8] = hi;           // term 0
            *(f16x8*)&z_s[(size_t)(16384) + (size_t)(kg * 64 + r) * 8] = lo; // term 1
        }
    }
    __syncthreads();

    const int m = tid & 31;        // col within 32-tile / A row
    const int h = (tid >> 5) & 1;  // lane half -> k split
    const int w = tid >> 6;        // wave id

    float bv[32];
    int bi[32];
    #pragma unroll
    for (int s = 0; s < 32; ++s) { bv[s] = 3.0e38f; bi[s] = 0; }

    for (int chunk = 0; chunk < 4; ++chunk) {
        const int cb = chunk * 256 + w * 64;
        const f16* ebp = emb_h + (size_t)h * 8192 + (size_t)(cb + m) * 8;

        f32x16 acc00, acc01, acc10, acc11;
        #pragma unroll
        for (int i = 0; i < 16; ++i) { acc00[i] = 0.f; acc01[i] = 0.f; acc10[i] = 0.f; acc11[i] = 0.f; }

        #pragma unroll 2
        for (int ks = 0; ks < 16; ++ks) {
            const f16* za = z_s + ks * 1024 + h * 512 + m * 8;
            f16x8 ah0 = *(const f16x8*)(za);
            f16x8 ah1 = *(const f16x8*)(za + 256);
            f16x8 ar0 = *(const f16x8*)(za + 16384);
            f16x8 ar1 = *(const f16x8*)(za + 16384 + 256);
            f16x8 b0 = *(const f16x8*)(ebp + (size_t)ks * 16384);
            f16x8 b1 = *(const f16x8*)(ebp + (size_t)ks * 16384 + 256);
            acc00 = __builtin_amdgcn_mfma_f32_32x32x16_f16(ah0, b0, acc00, 0, 0, 0);
            acc00 = __builtin_amdgcn_mfma_f32_32x32x16_f16(ar0, b0, acc00, 0, 0, 0);
            acc01 = __builtin_amdgcn_mfma_f32_32x32x16_f16(ah0, b1, acc01, 0, 0, 0);
            acc01 = __builtin_amdgcn_mfma_f32_32x32x16_f16(ar0, b1, acc01, 0, 0, 0);
            acc10 = __builtin_amdgcn_mfma_f32_32x32x16_f16(ah1, b0, acc10, 0, 0, 0);
            acc10 = __builtin_amdgcn_mfma_f32_32x32x16_f16(ar1, b0, acc10, 0, 0, 0);
            acc11 = __builtin_amdgcn_mfma_f32_32x32x16_f16(ah1, b1, acc11, 0, 0, 0);
            acc11 = __builtin_amdgcn_mfma_f32_32x32x16_f16(ar1, b1, acc11, 0, 0, 0);
        }

        // scores: c_sq - 2*dot ; running argmin (codes ascend -> strict <)
        const int code0 = cb + m;
        const int code1 = cb + 32 + m;
        const float cs0 = c_sq[code0];
        const float cs1 = c_sq[code1];
        #pragma unroll
        for (int reg = 0; reg < 16; ++reg) {
            upd(bv[reg], bi[reg], fmaf(-2.f, acc00[reg], cs0), code0);
            upd(bv[reg], bi[reg], fmaf(-2.f, acc01[reg], cs1), code1);
            upd(bv[16 + reg], bi[16 + reg], fmaf(-2.f, acc10[reg], cs0), code0);
            upd(bv[16 + reg], bi[16 + reg], fmaf(-2.f, acc11[reg], cs1), code1);
        }
    }

    // ---- butterfly argmin across the 32 lanes of each half ----
    #pragma unroll
    for (int s = 0; s < 32; ++s) {
        float v = bv[s];
        int i = bi[s];
        #pragma unroll
        for (int d = 16; d >= 1; d >>= 1) {
            float ov = __shfl_xor(v, d);
            int oi = __shfl_xor(i, d);
            if (ov < v || (ov == v && oi < i)) { v = ov; i = oi; }
        }
        bv[s] = v; bi[s] = i;
    }

    // lane m==0 of each half publishes its 32 row-slots
    if (m == 0) {
        #pragma unroll
        for (int s = 0; s < 32; ++s) {
            int rt = s >> 4, reg = s & 15;
            int row = rt * 32 + (reg & 3) + 8 * (reg >> 2) + 4 * h;
            bl_v[w][row] = bv[s];
            bl_i[w][row] = bi[s];
        }
    }
    __syncthreads();

    // combine 4 waves (disjoint code subsets), write idx + histogram
    if (tid < 64) {
        float v = bl_v[0][tid];
        int i = bl_i[0][tid];
        #pragma unroll
        for (int w2 = 1; w2 < 4; ++w2) {
            float ov = bl_v[w2][tid];
            int oi = bl_i[w2][tid];
            if (ov < v || (ov == v && oi < i)) { v = ov; i = oi; }
        }
        idx_out[n0 + tid] = i;
        atomicAdd(&counts[i], 1);
    }
}

// ---------------------------------------------------------------------------
// gather + transpose write + fused loss reduction (exact fp32 emb)
// ---------------------------------------------------------------------------
__global__ __launch_bounds__(256, 2)
void vq_gather_kernel(const float* __restrict__ z, const float* __restrict__ emb,
                      const int* __restrict__ idx, float* __restrict__ out,
                      float* __restrict__ loss_acc) {
    __shared__ float Q[64][257];
    __shared__ int idx_s[64];
    __shared__ float wsum[4];

    const int tid = threadIdx.x;
    const int n0 = blockIdx.x * 64;
    const int b = n0 >> 10;
    const int hw0 = n0 & 1023;

    if (tid < 64) idx_s[tid] = idx[n0 + tid];
    __syncthreads();

    {
        int r = tid >> 2;
        int q4 = tid & 3;
        const float* ep = emb + (size_t)idx_s[r] * DD;
        #pragma unroll
        for (int i = 0; i < 16; ++i) {
            int d = (q4 << 2) + (i << 4);
            float4 v = *(const float4*)(ep + d);
            Q[r][d] = v.x; Q[r][d + 1] = v.y; Q[r][d + 2] = v.z; Q[r][d + 3] = v.w;
        }
    }
    __syncthreads();

    float acc = 0.f;
    const int lane = tid & 63;
    const int w = tid >> 6;
    const size_t base = (size_t)b * (DD * 1024) + hw0 + lane;
    for (int c = w; c < DD; c += 4) {
        float q = Q[lane][c];
        size_t a = base + (size_t)c * 1024;
        float zv = z[a];
        out[a] = q;
        float d = q - zv;
        acc += d * d;
    }
    #pragma unroll
    for (int off = 32; off > 0; off >>= 1) acc += __shfl_down(acc, off);
    if (lane == 0) wsum[w] = acc;
    __syncthreads();
    if (tid == 0) atomicAdd(loss_acc, wsum[0] + wsum[1] + wsum[2] + wsum[3]);
}

// ---------------------------------------------------------------------------
// finalize: loss scalar + perplexity from counts
// ---------------------------------------------------------------------------
__global__ void vq_finalize_kernel(const int* __restrict__ counts,
                                   const float* __restrict__ loss_acc,
                                   float* __restrict__ out_tail) {
    __shared__ float wsum[4];
    const int tid = threadIdx.x;
    float s = 0.f;
    #pragma unroll
    for (int k = tid; k < KC; k += 256) {
        float p = (float)counts[k] * (1.0f / (float)NROWS);
        s += p * logf(p + 1e-10f);
    }
    #pragma unroll
    for (int off = 32; off > 0; off >>= 1) s += __shfl_down(s, off);
    const int lane = tid & 63;
    const int w = tid >> 6;
    if (lane == 0) wsum[w] = s;
    __syncthreads();
    if (tid == 0) {
        float ent = wsum[0] + wsum[1] + wsum[2] + wsum[3];
        out_tail[0] = 1.25f * loss_acc[0] * (1.0f / (float)NELEM);
        out_tail[1] = expf(-ent);
    }
}

// ---------------------------------------------------------------------------
extern "C" void kernel_launch(void* const* d_in, const int* in_sizes, int n_in,
                              void* d_out, int out_size, void* d_ws, size_t ws_size,
                              hipStream_t stream) {
    const float* z = (const float*)d_in[0];    // (32,256,32,32)
    const float* emb = (const float*)d_in[1];  // (1024,256)
    float* out = (float*)d_out;                // 8388608 + 2

    // ws layout (bytes): emb_h [0,524288) | c_sq | idx | counts | loss
    char* wsb = (char*)d_ws;
    f16* emb_h = (f16*)wsb;
    float* c_sq = (float*)(wsb + 524288);
    int* idx = (int*)(wsb + 528384);
    int* counts = (int*)(wsb + 659456);
    float* loss_acc = (float*)(wsb + 663552);

    hipLaunchKernelGGL(vq_init_kernel, dim3(4), dim3(256), 0, stream, counts, loss_acc);
    hipLaunchKernelGGL(vq_csq_kernel, dim3(256), dim3(256), 0, stream, emb, c_sq);
    hipLaunchKernelGGL(vq_embh_kernel, dim3(128), dim3(256), 0, stream, emb, emb_h);
    hipLaunchKernelGGL(vq_dist_kernel, dim3(512), dim3(256), 0, stream,
                       z, emb_h, c_sq, idx, counts);
    hipLaunchKernelGGL(vq_gather_kernel, dim3(512), dim3(256), 0, stream,
                       z, emb, idx, out, loss_acc);
    hipLaunchKernelGGL(vq_finalize_kernel, dim3(1), dim3(256), 0, stream,
                       counts, loss_acc, out + NELEM);
}

// Round 3
// 138.212 us; speedup vs baseline: 3.0521x; 1.1917x over previous
//
#include <hip/hip_runtime.h>
#include <math.h>

// Problem constants
#define KC 1024       // num codes
#define DD 256        // embedding dim
#define NROWS 32768   // 32 * 32 * 32 (B*H*W)
#define NELEM 8388608 // NROWS * DD

typedef _Float16 f16;
typedef __attribute__((ext_vector_type(8))) _Float16 f16x8;
typedef __attribute__((ext_vector_type(16))) float f32x16;

// ---------------------------------------------------------------------------
// prep: counts/loss init + c_sq (exact fp32) + emb -> fp16 swizzled
// grid 256 x 256.  emb_h layout: [kg 32][code 1024][8]
// ---------------------------------------------------------------------------
__global__ void vq_prep_kernel(const float* __restrict__ emb, f16* __restrict__ emb_h,
                               float* __restrict__ c_sq, int* __restrict__ counts,
                               float* __restrict__ loss_acc) {
    const int tid = threadIdx.x;
    const int gt = blockIdx.x * 256 + tid;
    if (gt < KC) counts[gt] = 0;
    if (gt == 0) *loss_acc = 0.0f;
    // c_sq: 4 codes/block, one per wave
    {
        int k = blockIdx.x * 4 + (tid >> 6);
        int lane = tid & 63;
        float4 v = *(const float4*)(emb + (size_t)k * DD + lane * 4);
        float s = v.x * v.x + v.y * v.y + v.z * v.z + v.w * v.w;
        #pragma unroll
        for (int off = 32; off > 0; off >>= 1) s += __shfl_down(s, off);
        if (lane == 0) c_sq[k] = s;
    }
    // embh: blocks 0..127 cover 32768 elements
    if (gt < 32768) {
        int code = gt & 1023;
        int kg = gt >> 10;
        const float* p = emb + (size_t)code * DD + kg * 8;
        float4 v0 = *(const float4*)p;
        float4 v1 = *(const float4*)(p + 4);
        f16x8 h;
        h[0] = (f16)v0.x; h[1] = (f16)v0.y; h[2] = (f16)v0.z; h[3] = (f16)v0.w;
        h[4] = (f16)v1.x; h[5] = (f16)v1.y; h[6] = (f16)v1.z; h[7] = (f16)v1.w;
        *(f16x8*)(emb_h + (size_t)gt * 8) = h;
    }
}

// ---------------------------------------------------------------------------
// Fused dist + argmin + gather + transpose-write + loss.
// Block = 64 rows. Phase A: z tile -> LDS fp16 [kg32][row64][8] (32 KB).
// Phase B: MFMA 32x32x16 f16, 4 chunks x (wave-local 64 codes), running
// argmin in registers on C-layout, butterfly + LDS combine.
// Phase C: Qh transpose (overlays z_s, row stride 264 halfs) -> coalesced
// channel-major out writes + fused (q-z)^2 loss.
// LDS ~36 KB -> 4 blocks LDS-wise; regs -> 3 blocks/CU.
// ---------------------------------------------------------------------------
__device__ __forceinline__ void upd(float& bv, int& bi, float v, int i) {
    if (v < bv) { bv = v; bi = i; }
}

__global__ __launch_bounds__(256, 3)
void vq_dist_kernel(const float* __restrict__ z, const float* __restrict__ emb,
                    const f16* __restrict__ emb_h, const float* __restrict__ c_sq,
                    int* __restrict__ counts, float* __restrict__ out,
                    float* __restrict__ loss_acc) {
    __shared__ __align__(16) f16 smem[64 * 264]; // phaseA/B: z_s (16384 used); phaseC: Qh
    __shared__ float bl_v[4][64];
    __shared__ int bl_i[4][64];
    __shared__ int idx_s[64];
    __shared__ float wsum[4];

    const int tid = threadIdx.x;
    const int n0 = blockIdx.x * 64;
    const int b = n0 >> 10;
    const int hw0 = n0 & 1023;

    // ---- Phase A: stage z tile fp16 (single term) ----
    {
        const int r = tid & 63;
        const int kq = tid >> 6;  // 0..3
        const float* zp = z + (size_t)b * (DD * 1024) + hw0 + r;
        #pragma unroll
        for (int it = 0; it < 8; ++it) {
            int kg = kq * 8 + it;
            f16x8 hv;
            #pragma unroll
            for (int j = 0; j < 8; ++j) hv[j] = (f16)zp[(size_t)(kg * 8 + j) * 1024];
            *(f16x8*)&smem[(kg * 64 + r) * 8] = hv;
        }
    }
    __syncthreads();

    const int m = tid & 31;        // col within 32-tile / A row
    const int h = (tid >> 5) & 1;  // k-half
    const int w = tid >> 6;        // wave id

    float bv[32];
    int bi[32];
    #pragma unroll
    for (int s = 0; s < 32; ++s) { bv[s] = 3.0e38f; bi[s] = 0; }

    // ---- Phase B: MFMA + running argmin ----
    for (int chunk = 0; chunk < 4; ++chunk) {
        const int cb = chunk * 256 + w * 64;
        const f16* ebp = emb_h + (size_t)h * 8192 + (size_t)(cb + m) * 8;

        f32x16 acc00, acc01, acc10, acc11;
        #pragma unroll
        for (int i = 0; i < 16; ++i) { acc00[i] = 0.f; acc01[i] = 0.f; acc10[i] = 0.f; acc11[i] = 0.f; }

        #pragma unroll 4
        for (int ks = 0; ks < 16; ++ks) {
            const f16* za = smem + ks * 1024 + h * 512 + m * 8;
            f16x8 a0 = *(const f16x8*)(za);
            f16x8 a1 = *(const f16x8*)(za + 256);
            f16x8 b0 = *(const f16x8*)(ebp + (size_t)ks * 16384);
            f16x8 b1 = *(const f16x8*)(ebp + (size_t)ks * 16384 + 256);
            acc00 = __builtin_amdgcn_mfma_f32_32x32x16_f16(a0, b0, acc00, 0, 0, 0);
            acc01 = __builtin_amdgcn_mfma_f32_32x32x16_f16(a0, b1, acc01, 0, 0, 0);
            acc10 = __builtin_amdgcn_mfma_f32_32x32x16_f16(a1, b0, acc10, 0, 0, 0);
            acc11 = __builtin_amdgcn_mfma_f32_32x32x16_f16(a1, b1, acc11, 0, 0, 0);
        }

        const int code0 = cb + m;
        const int code1 = cb + 32 + m;
        const float cs0 = c_sq[code0];
        const float cs1 = c_sq[code1];
        #pragma unroll
        for (int reg = 0; reg < 16; ++reg) {
            upd(bv[reg], bi[reg], fmaf(-2.f, acc00[reg], cs0), code0);
            upd(bv[reg], bi[reg], fmaf(-2.f, acc01[reg], cs1), code1);
            upd(bv[16 + reg], bi[16 + reg], fmaf(-2.f, acc10[reg], cs0), code0);
            upd(bv[16 + reg], bi[16 + reg], fmaf(-2.f, acc11[reg], cs1), code1);
        }
    }

    // butterfly argmin across the 32 lanes of each half
    #pragma unroll
    for (int s = 0; s < 32; ++s) {
        float v = bv[s];
        int i = bi[s];
        #pragma unroll
        for (int d = 16; d >= 1; d >>= 1) {
            float ov = __shfl_xor(v, d);
            int oi = __shfl_xor(i, d);
            if (ov < v || (ov == v && oi < i)) { v = ov; i = oi; }
        }
        bv[s] = v; bi[s] = i;
    }
    if (m == 0) {
        #pragma unroll
        for (int s = 0; s < 32; ++s) {
            int rt = s >> 4, reg = s & 15;
            int row = rt * 32 + (reg & 3) + 8 * (reg >> 2) + 4 * h;
            bl_v[w][row] = bv[s];
            bl_i[w][row] = bi[s];
        }
    }
    __syncthreads();

    // combine 4 waves (disjoint code subsets) -> idx_s + histogram
    if (tid < 64) {
        float v = bl_v[0][tid];
        int i = bl_i[0][tid];
        #pragma unroll
        for (int w2 = 1; w2 < 4; ++w2) {
            float ov = bl_v[w2][tid];
            int oi = bl_i[w2][tid];
            if (ov < v || (ov == v && oi < i)) { v = ov; i = oi; }
        }
        idx_s[tid] = i;
        atomicAdd(&counts[i], 1);
    }
    __syncthreads();

    // ---- Phase C1: stage Qh[r][c] = fp16(emb[idx_s[r]][c]), stride 264 ----
    {
        int r = tid >> 2;
        int part = tid & 3;
        const float* ep = emb + (size_t)idx_s[r] * DD + part * 64;
        f16* qrow = smem + r * 264 + part * 64;
        #pragma unroll
        for (int i = 0; i < 8; ++i) {
            float4 v0 = *(const float4*)(ep + i * 8);
            float4 v1 = *(const float4*)(ep + i * 8 + 4);
            f16x8 hv;
            hv[0] = (f16)v0.x; hv[1] = (f16)v0.y; hv[2] = (f16)v0.z; hv[3] = (f16)v0.w;
            hv[4] = (f16)v1.x; hv[5] = (f16)v1.y; hv[6] = (f16)v1.z; hv[7] = (f16)v1.w;
            *(f16x8*)(qrow + i * 8) = hv;
        }
    }
    __syncthreads();

    // ---- Phase C2: coalesced channel-major writes + loss ----
    float acc = 0.f;
    {
        const int lane = tid & 63;
        const size_t base = (size_t)b * (DD * 1024) + hw0 + lane;
        const f16* qr = smem + lane * 264;
        for (int cg = w; cg < 32; cg += 4) {
            f16x8 qv = *(const f16x8*)(qr + cg * 8);
            #pragma unroll
            for (int j = 0; j < 8; ++j) {
                int c = cg * 8 + j;
                size_t a = base + (size_t)c * 1024;
                float q = (float)qv[j];
                float zv = z[a];
                out[a] = q;
                float d = q - zv;
                acc += d * d;
            }
        }
    }
    #pragma unroll
    for (int off = 32; off > 0; off >>= 1) acc += __shfl_down(acc, off);
    if ((tid & 63) == 0) wsum[w] = acc;
    __syncthreads();
    if (tid == 0) atomicAdd(loss_acc, wsum[0] + wsum[1] + wsum[2] + wsum[3]);
}

// ---------------------------------------------------------------------------
// finalize: loss scalar + perplexity from counts
// ---------------------------------------------------------------------------
__global__ void vq_finalize_kernel(const int* __restrict__ counts,
                                   const float* __restrict__ loss_acc,
                                   float* __restrict__ out_tail) {
    __shared__ float wsum[4];
    const int tid = threadIdx.x;
    float s = 0.f;
    #pragma unroll
    for (int k = tid; k < KC; k += 256) {
        float p = (float)counts[k] * (1.0f / (float)NROWS);
        s += p * logf(p + 1e-10f);
    }
    #pragma unroll
    for (int off = 32; off > 0; off >>= 1) s += __shfl_down(s, off);
    const int lane = tid & 63;
    const int w = tid >> 6;
    if (lane == 0) wsum[w] = s;
    __syncthreads();
    if (tid == 0) {
        float ent = wsum[0] + wsum[1] + wsum[2] + wsum[3];
        out_tail[0] = 1.25f * loss_acc[0] * (1.0f / (float)NELEM);
        out_tail[1] = expf(-ent);
    }
}

// ---------------------------------------------------------------------------
extern "C" void kernel_launch(void* const* d_in, const int* in_sizes, int n_in,
                              void* d_out, int out_size, void* d_ws, size_t ws_size,
                              hipStream_t stream) {
    const float* z = (const float*)d_in[0];    // (32,256,32,32)
    const float* emb = (const float*)d_in[1];  // (1024,256)
    float* out = (float*)d_out;                // 8388608 + 2

    // ws layout (bytes): emb_h [0,524288) | c_sq | counts | loss
    char* wsb = (char*)d_ws;
    f16* emb_h = (f16*)wsb;
    float* c_sq = (float*)(wsb + 524288);
    int* counts = (int*)(wsb + 528384);
    float* loss_acc = (float*)(wsb + 532480);

    hipLaunchKernelGGL(vq_prep_kernel, dim3(256), dim3(256), 0, stream,
                       emb, emb_h, c_sq, counts, loss_acc);
    hipLaunchKernelGGL(vq_dist_kernel, dim3(512), dim3(256), 0, stream,
                       z, emb, emb_h, c_sq, counts, out, loss_acc);
    hipLaunchKernelGGL(vq_finalize_kernel, dim3(1), dim3(256), 0, stream,
                       counts, loss_acc, out + NELEM);
}